// Round 1
// baseline (89.385 us; speedup 1.0000x reference)
//
#include <hip/hip_runtime.h>

#define EPS 1e-6f
#define NPAIR 12

typedef float v2f __attribute__((ext_vector_type(2)));

__device__ __forceinline__ v2f fma2(v2f a, v2f b, v2f c) {
    return __builtin_elementwise_fma(a, b, c);
}
__device__ __forceinline__ v2f max2(v2f a, v2f b) {
    return __builtin_elementwise_max(a, b);
}

// Single fused kernel: per-joint constant folding is done inline from the raw
// uniform inputs (scalar-cached s_loads), eliminating fold_kernel and d_ws.
// 1 point/thread, 2 joints/iter (v2f lanes), no-normalize rads form.
__global__ __launch_bounds__(256, 4) void shcaster_kernel(
    const float* __restrict__ xyz,
    const float* __restrict__ vdir,
    const float* __restrict__ trf,    // [24][16]
    const float* __restrict__ shf,    // [24][9]
    const float* __restrict__ locs,   // [24][3]
    float* __restrict__ out,
    int n)
{
    const int i = blockIdx.x * blockDim.x + threadIdx.x;
    if (i >= n) return;

    const float px = xyz[3 * i + 0];
    const float py = xyz[3 * i + 1];
    const float pz = xyz[3 * i + 2];
    const float vx = vdir[3 * i + 0];   // load early; used in epilogue
    const float vy = vdir[3 * i + 1];
    const float vz = vdir[3 * i + 2];

    const v2f px2 = {px, px};
    const v2f py2 = {py, py};
    const v2f pz2 = {pz, pz};
    const v2f one2  = {1.f, 1.f};
    const v2f zero2 = {0.f, 0.f};
    const v2f eps2  = {EPS, EPS};

    const v2f C0v  = {0.28209479177387814f, 0.28209479177387814f};
    const v2f C1v  = {0.4886025119029199f,  0.4886025119029199f};
    const v2f C2av = {1.0925484305920792f,  1.0925484305920792f};
    const v2f C6v  = {0.31539156525252005f, 0.31539156525252005f};
    const v2f C8v  = {0.5462742152960396f,  0.5462742152960396f};
    const v2f half2 = {0.5f, 0.5f};

    v2f wsum2 = zero2;
    v2f Ta2[12];
    #pragma unroll
    for (int k = 0; k < 12; ++k) Ta2[k] = zero2;

    #pragma unroll 2
    for (int pp = 0; pp < NPAIR; ++pp) {
        // wave-uniform raw-input pointers -> scalar loads
        const float* A  = trf  + 32 * pp;        // joint 2pp   rows
        const float* B  = A + 16;                // joint 2pp+1 rows
        const float* FA = shf  + 18 * pp;
        const float* FB = FA + 9;
        const float* LA = locs + 6 * pp;
        const float* LB = LA + 3;

        v2f T[12];
        #pragma unroll
        for (int k = 0; k < 12; ++k) T[k] = (v2f){A[k], B[k]};

        const v2f tmlx = {A[3]  - LA[0], B[3]  - LB[0]};
        const v2f tmly = {A[7]  - LA[1], B[7]  - LB[1]};
        const v2f tmlz = {A[11] - LA[2], B[11] - LB[2]};

        // u = R.p + (t - loc)  — vd = -u; d2, quad, |u| all even in u
        const v2f ux = fma2(T[0], px2, fma2(T[1], py2, fma2(T[2],  pz2, tmlx)));
        const v2f uy = fma2(T[4], px2, fma2(T[5], py2, fma2(T[6],  pz2, tmly)));
        const v2f uz = fma2(T[8], px2, fma2(T[9], py2, fma2(T[10], pz2, tmlz)));

        const v2f xx = ux * ux;
        const v2f yy = uy * uy;
        const v2f zz = uz * uz;
        v2f d2 = (xx + yy) + zz;
        d2 = max2(d2, (v2f){1e-24f, 1e-24f});

        // rsq kicks off now; lin/quad evaluate in parallel with its latency
        const v2f inv = {__builtin_amdgcn_rsqf(d2.x), __builtin_amdgcn_rsqf(d2.y)};

        const v2f F0 = {FA[0], FB[0]};
        const v2f F1 = {FA[1], FB[1]};
        const v2f F2 = {FA[2], FB[2]};
        const v2f F3 = {FA[3], FB[3]};
        const v2f F4 = {FA[4], FB[4]};
        const v2f F5 = {FA[5], FB[5]};
        const v2f F6 = {FA[6], FB[6]};
        const v2f F7 = {FA[7], FB[7]};
        const v2f F8 = {FA[8], FB[8]};

        const v2f f02 = fma2(C0v, F0, half2);

        // lin = -C1*(F3*ux + F1*uy - F2*uz);  -lin*inv = +C1*linc*inv
        const v2f linc = fma2(F3, ux, fma2(F1, uy, F2 * (-uz)));

        // quad = C2a*(F4*xy - F5*yz - F7*xz) + C6*F6*(2zz-xx-yy) + C8*F8*(xx-yy)
        const v2f xy = ux * uy;
        const v2f yz = uy * uz;
        const v2f xz = ux * uz;
        v2f q1 = fma2(F5, -yz, F4 * xy);
        q1 = fma2(F7, -xz, q1);
        const v2f s2 = (zz - xx) + (zz - yy);
        const v2f dd = xx - yy;
        const v2f c62 = F6 * C6v;
        const v2f c82 = F8 * C8v;
        v2f quad = fma2(c82, dd, q1 * C2av);
        quad = fma2(c62, s2, quad);

        const v2f len   = d2 * inv;        // = |u|
        const v2f inv2  = inv * inv;       // = 1/d2
        const v2f c1inv = C1v * inv;

        // rads = f0 + C1*linc*inv + quad*inv2
        v2f rads = fma2(quad, inv2, f02);
        rads = fma2(linc, c1inv, rads);
        rads = max2(rads, zero2);

        const v2f rm = max2(rads, eps2);
        const v2f rc = {__builtin_amdgcn_rcpf(rm.x), __builtin_amdgcn_rcpf(rm.y)};
        v2f rel = max2(fma2(-len, rc, one2), zero2);
        rel.x = (rads.x < EPS) ? 0.f : rel.x;
        rel.y = (rads.y < EPS) ? 0.f : rel.y;

        wsum2 += rel;
        #pragma unroll
        for (int k = 0; k < 12; ++k) Ta2[k] = fma2(rel, T[k], Ta2[k]);
    }

    const float wsum = wsum2.x + wsum2.y;
    float Ta[12];
    #pragma unroll
    for (int k = 0; k < 12; ++k) Ta[k] = Ta2[k].x + Ta2[k].y;

    const float inv_w = __builtin_amdgcn_rcpf(fmaxf(wsum, EPS));
    const bool valid = wsum > EPS;

    const float axo = fmaf(Ta[0], px, fmaf(Ta[1], py, fmaf(Ta[2],  pz, Ta[3])))  * inv_w;
    const float ayo = fmaf(Ta[4], px, fmaf(Ta[5], py, fmaf(Ta[6],  pz, Ta[7])))  * inv_w;
    const float azo = fmaf(Ta[8], px, fmaf(Ta[9], py, fmaf(Ta[10], pz, Ta[11]))) * inv_w;

    // view = o - T(p-v)/w = R.v * inv_w  (translation cancels); invalid -> v
    const float wxv = fmaf(Ta[0], vx, fmaf(Ta[1], vy, Ta[2]  * vz)) * inv_w;
    const float wyv = fmaf(Ta[4], vx, fmaf(Ta[5], vy, Ta[6]  * vz)) * inv_w;
    const float wzv = fmaf(Ta[8], vx, fmaf(Ta[9], vy, Ta[10] * vz)) * inv_w;

    out[3 * i + 0] = valid ? axo : px;
    out[3 * i + 1] = valid ? ayo : py;
    out[3 * i + 2] = valid ? azo : pz;
    float* out2 = out + (size_t)3 * n;
    out2[3 * i + 0] = valid ? wxv : vx;
    out2[3 * i + 1] = valid ? wyv : vy;
    out2[3 * i + 2] = valid ? wzv : vz;
}

extern "C" void kernel_launch(void* const* d_in, const int* in_sizes, int n_in,
                              void* d_out, int out_size, void* d_ws, size_t ws_size,
                              hipStream_t stream) {
    const int n = (out_size > 0) ? (out_size / 6) : 524288;
    const int big = 3 * n;

    const float* xyz  = nullptr;
    const float* vdir = nullptr;
    const float* trf  = nullptr;
    const float* shf  = nullptr;
    const float* locs = nullptr;
    int bigSeen = 0;
    for (int k = 0; k < n_in; ++k) {
        const int s = in_sizes[k];
        if (s == big) {
            if (bigSeen++ == 0) xyz = (const float*)d_in[k];
            else                vdir = (const float*)d_in[k];
        } else if (s == 384) {
            trf = (const float*)d_in[k];
        } else if (s == 216) {
            shf = (const float*)d_in[k];
        } else if (s == 72) {
            locs = (const float*)d_in[k];
        }
    }
    if (!xyz || !vdir || !trf || !shf || !locs) {
        xyz  = (const float*)d_in[0];
        vdir = (const float*)d_in[1];
        trf  = (const float*)d_in[2];
        shf  = (const float*)d_in[n_in >= 6 ? 4 : 3];
        locs = (const float*)d_in[n_in >= 6 ? 5 : 4];
    }

    float* out = (float*)d_out;

    const int block = 256;
    const int grid = (n + block - 1) / block;
    shcaster_kernel<<<grid, block, 0, stream>>>(xyz, vdir, trf, shf, locs, out, n);
}